// Round 1
// baseline (46986.981 us; speedup 1.0000x reference)
//
#include <hip/hip_runtime.h>
#include <cstdint>
#include <cmath>

#define DEVI __device__ __forceinline__

constexpr int B_ = 16, TENC_ = 168, TBERT_ = 96, TOUT_ = 200;
constexpr int NMEL_ = 80, ENC_ = 512, ARNN_ = 1024, PRE_ = 256, ATT_ = 128, NF_ = 32, KCV_ = 31;

// ---------------- workspace layout (float offsets) ----------------
constexpr size_t o_qWTa = 0;                               // [1024][128] transposed attn_q
constexpr size_t o_qWTb = o_qWTa + 1024*128;
constexpr size_t o_pall  = o_qWTb + 1024*128;              // [T][B][PRE]
constexpr size_t o_pball = o_pall + (size_t)TOUT_*B_*PRE_;
constexpr size_t o_pmem  = o_pball + (size_t)TOUT_*B_*PRE_; // [B][TENC][ATT]
constexpr size_t o_pbert = o_pmem + (size_t)B_*TENC_*ATT_;  // [B][TBERT][ATT]
constexpr size_t o_state = o_pbert + (size_t)B_*TBERT_*ATT_;
constexpr size_t o_ah   = o_state;                  // [2][B][ARNN] double-buffered
constexpr size_t o_ahb  = o_ah  + 2*B_*ARNN_;
constexpr size_t o_ac   = o_ahb + 2*B_*ARNN_;
constexpr size_t o_acb  = o_ac  + B_*ARNN_;
constexpr size_t o_dh   = o_acb + B_*ARNN_;
constexpr size_t o_dc   = o_dh  + B_*ARNN_;
constexpr size_t o_dhb  = o_dc  + B_*ARNN_;
constexpr size_t o_dcb  = o_dhb + B_*ARNN_;
constexpr size_t o_ctx  = o_dcb + B_*ARNN_;         // [B][ENC]
constexpr size_t o_ctxb = o_ctx + B_*ENC_;
constexpr size_t o_aw   = o_ctxb+ B_*ENC_;          // [B][TENC]
constexpr size_t o_awc  = o_aw  + B_*TENC_;
constexpr size_t o_awb  = o_awc + B_*TENC_;         // [B][TBERT]
constexpr size_t o_awcb = o_awb + B_*TBERT_;
constexpr size_t o_zend = o_awcb+ B_*TBERT_;
constexpr size_t ZCOUNT = o_zend - o_state;
constexpr size_t o_gd   = o_zend;                   // drnn gates [4096][B]
constexpr size_t o_gdb  = o_gd + 4096*B_;
constexpr size_t o_dhall   = o_gdb + 4096*B_;       // [T][B][DRNN]
constexpr size_t o_ctxall  = o_dhall + (size_t)TOUT_*B_*ARNN_;
constexpr size_t o_ctxball = o_ctxall + (size_t)TOUT_*B_*ENC_;
// total ≈ 9.3M floats ≈ 37.3 MB

// output offsets (floats)
constexpr size_t OO_MEL  = 0;
constexpr size_t OO_GATE = (size_t)B_*NMEL_*TOUT_;
constexpr size_t OO_AL   = OO_GATE + (size_t)B_*TOUT_;
constexpr size_t OO_ALB  = OO_AL + (size_t)B_*TOUT_*TENC_;

DEVI float sigf(float x) { return 1.f / (1.f + expf(-x)); }
DEVI int imin(int a, int b) { return a < b ? a : b; }
DEVI int imax(int a, int b) { return a > b ? a : b; }

// dot of n (multiple of 4) floats, 4 independent FMA chains
DEVI float dotseg(const float* __restrict__ w, const float* __restrict__ x, int n) {
  const float4* wp = reinterpret_cast<const float4*>(w);
  const float4* xp = reinterpret_cast<const float4*>(x);
  float a0 = 0, a1 = 0, a2 = 0, a3 = 0;
  int n4 = n >> 2;
#pragma unroll 4
  for (int i = 0; i < n4; ++i) {
    float4 wv = wp[i], xv = xp[i];
    a0 = fmaf(wv.x, xv.x, a0); a1 = fmaf(wv.y, xv.y, a1);
    a2 = fmaf(wv.z, xv.z, a2); a3 = fmaf(wv.w, xv.w, a3);
  }
  return (a0 + a1) + (a2 + a3);
}

// ================= prolog: prenet(all t), pmem, pbert, q-transposes, zero states =================
__global__ __launch_bounds__(256) void k_prolog(
    const float* __restrict__ dec, const float* __restrict__ pw1, const float* __restrict__ pw2,
    const float* __restrict__ pbw1, const float* __restrict__ pbw2,
    const float* __restrict__ memory, const float* __restrict__ embeddings,
    const float* __restrict__ am, const float* __restrict__ abm,
    const float* __restrict__ aq, const float* __restrict__ abq,
    float* __restrict__ ws)
{
  __shared__ float smem[10240];
  int bid = blockIdx.x, tid = threadIdx.x;
  if (bid < 200) {
    // prenet for frame t (teacher-forced input; t=0 -> zeros)
    int t = bid;
    float* xl  = smem;                // [16][80]
    float* h1  = smem + 1280;         // [16][256]
    float* h1b = smem + 1280 + 4096;  // [16][256]
    for (int i = tid; i < 16*80; i += 256) {
      int b = i / 80, m = i % 80;
      xl[i] = (t == 0) ? 0.f : dec[((size_t)b*80 + m)*200 + (t-1)];
    }
    __syncthreads();
    int j = tid;
    for (int b = 0; b < 16; ++b) {
      const float* x = xl + b*80;
      float a1 = 0, a2 = 0;
#pragma unroll 4
      for (int m = 0; m < 80; ++m) { a1 = fmaf(pw1[j*80+m], x[m], a1); a2 = fmaf(pbw1[j*80+m], x[m], a2); }
      h1[b*256+j]  = fmaxf(a1, 0.f);
      h1b[b*256+j] = fmaxf(a2, 0.f);
    }
    __syncthreads();
    for (int b = 0; b < 16; ++b) {
      float a1 = 0, a2 = 0;
#pragma unroll 4
      for (int k = 0; k < 256; ++k) { a1 = fmaf(pw2[j*256+k], h1[b*256+k], a1); a2 = fmaf(pbw2[j*256+k], h1b[b*256+k], a2); }
      ws[o_pall  + ((size_t)t*16+b)*256 + j] = fmaxf(a1, 0.f);
      ws[o_pball + ((size_t)t*16+b)*256 + j] = fmaxf(a2, 0.f);
    }
  } else if (bid < 368) {
    // pmem: rows (b,t) flattened; 16 rows per block
    int r0 = (bid - 200) * 16;
    float* ml = smem;  // [16][512]
    for (int i = tid; i < 16*512; i += 256) ml[i] = memory[(size_t)r0*512 + i];
    __syncthreads();
    int a = tid & 127, ro = tid >> 7;
    for (int row = ro; row < 16; row += 2) {
      const float* x = ml + row*512; const float* w = am + (size_t)a*512;
      float acc = 0;
#pragma unroll 4
      for (int e = 0; e < 512; ++e) acc = fmaf(w[e], x[e], acc);
      ws[o_pmem + (size_t)(r0+row)*128 + a] = acc;
    }
  } else if (bid < 464) {
    int r0 = (bid - 368) * 16;
    float* ml = smem;
    for (int i = tid; i < 16*512; i += 256) ml[i] = embeddings[(size_t)r0*512 + i];
    __syncthreads();
    int a = tid & 127, ro = tid >> 7;
    for (int row = ro; row < 16; row += 2) {
      const float* x = ml + row*512; const float* w = abm + (size_t)a*512;
      float acc = 0;
#pragma unroll 4
      for (int e = 0; e < 512; ++e) acc = fmaf(w[e], x[e], acc);
      ws[o_pbert + (size_t)(r0+row)*128 + a] = acc;
    }
  } else if (bid < 466) {
    const float* src = (bid == 464) ? aq : abq;
    float* dst = ws + ((bid == 464) ? o_qWTa : o_qWTb);
    for (int i = tid; i < 1024*128; i += 256) {
      int k = i >> 7, a = i & 127;
      dst[i] = src[(size_t)a*1024 + k];
    }
  } else {
    int zi = bid - 466;  // 8 zero blocks
    for (size_t i = (size_t)zi*256 + tid; i < ZCOUNT; i += 8*256) ws[o_state + i] = 0.f;
  }
}

// ================= per-step kernel 1: all LSTM gate GEMMs =================
// blocks [0,45)=arnn(t) [45,90)=arnnb(t) (with fused pointwise)
// blocks [90,190)=drnn(t-1) gates, [190,256)=drnnb(t-1) gates (pointwise deferred to k_step2)
__global__ __launch_bounds__(512) void k_step1(
    int t,
    const float* __restrict__ a_wih, const float* __restrict__ a_whh, const float* __restrict__ a_b,
    const float* __restrict__ ab_wih, const float* __restrict__ ab_whh, const float* __restrict__ ab_b,
    const float* __restrict__ d_wih, const float* __restrict__ d_whh,
    const float* __restrict__ db_wih, const float* __restrict__ db_whh,
    float* __restrict__ ws)
{
  __shared__ float xs[16][964];   // x transposed-by-batch tile, 16B-aligned rows, 2-way-free banks
  __shared__ float glds[4][128];
  int bid = blockIdx.x, tid = threadIdx.x;
  int lane = tid & 63, b = lane & 15, q = lane >> 4, w8 = tid >> 6;

  if (bid < 90) {
    if (t >= TOUT_) return;
    bool isB = bid >= 45; int ai = isB ? bid - 45 : bid;
    const float* wih  = isB ? ab_wih : a_wih;
    const float* whh  = isB ? ab_whh : a_whh;
    const float* bias = isB ? ab_b : a_b;
    const float* pall = ws + (isB ? o_pball : o_pall) + (size_t)t*B_*PRE_;
    const float* ctxS = ws + (isB ? o_ctxb : o_ctx);
    const float* hprev = ws + (isB ? o_ahb : o_ah) + (size_t)((t+1)&1)*(B_*ARNN_);
    float* hcur = ws + (isB ? o_ahb : o_ah) + (size_t)(t&1)*(B_*ARNN_);
    float* cst  = ws + (isB ? o_acb : o_ac);
    int u0 = ai*1024/45, u1 = (ai+1)*1024/45;   // <=23 units
    int gate = w8 & 3, qq = ((w8 >> 2) << 2) + q;  // unit-sublane 0..7
    float acc[3] = {0.f, 0.f, 0.f};
    for (int k0 = 0; k0 < 1792; k0 += 960) {
      int k1 = imin(1792, k0 + 960), n = k1 - k0;
      for (int bb = 0; bb < 16; ++bb)
        for (int k = tid; k < n; k += 512) {
          int kk = k0 + k; float v;
          if (kk < 256)      v = pall[bb*256 + kk];
          else if (kk < 768) v = ctxS[bb*512 + (kk-256)];
          else               v = hprev[bb*1024 + (kk-768)];
          xs[bb][k] = v;
        }
      __syncthreads();
#pragma unroll
      for (int p = 0; p < 3; ++p) {
        int u = u0 + p*8 + qq;
        if (u < u1) {
          int row = gate*1024 + u;
          int s1 = imin(k1, 768);
          if (s1 > k0) acc[p] += dotseg(wih + (size_t)row*768 + k0, &xs[b][0], s1 - k0);
          int h0 = imax(k0, 768);
          if (k1 > h0) acc[p] += dotseg(whh + (size_t)row*1024 + (h0-768), &xs[b][h0-k0], k1 - h0);
        }
      }
      __syncthreads();
    }
#pragma unroll
    for (int p = 0; p < 3; ++p) {
      int u = u0 + p*8 + qq;
      glds[gate][qq*16 + b] = (u < u1) ? acc[p] + bias[gate*1024 + u] : 0.f;
      __syncthreads();
      if (tid < 128) {
        int b2 = tid & 15, q2 = tid >> 4;
        int u2 = u0 + p*8 + q2;
        if (u2 < u1) {
          float gi = glds[0][q2*16+b2], gf = glds[1][q2*16+b2];
          float gg = glds[2][q2*16+b2], go = glds[3][q2*16+b2];
          float co = cst[b2*1024 + u2];
          float cn = sigf(gf)*co + sigf(gi)*tanhf(gg);
          float hn = sigf(go)*tanhf(cn);
          cst[b2*1024 + u2] = cn;
          hcur[b2*1024 + u2] = hn;
        }
      }
      __syncthreads();
    }
  } else if (bid < 190) {
    if (t == 0) return;  // drnn(t-1)
    int ci = bid - 90;
    int r0 = ci*4096/100, r1 = (ci+1)*4096/100;  // <=41 rows
    const float* ahp  = ws + o_ah  + (size_t)((t-1)&1)*(B_*ARNN_);
    const float* ahbp = ws + o_ahb + (size_t)((t-1)&1)*(B_*ARNN_);
    const float* ctxS = ws + o_ctx;
    const float* ctxbS= ws + o_ctxb;
    const float* dhS  = ws + o_dh;
    float* gout = ws + o_gd;
    float acc[2] = {0.f, 0.f};
    for (int k0 = 0; k0 < 4096; k0 += 960) {
      int k1 = imin(4096, k0 + 960), n = k1 - k0;
      for (int bb = 0; bb < 16; ++bb)
        for (int k = tid; k < n; k += 512) {
          int kk = k0 + k; float v;
          if (kk < 1024)      v = ahp[bb*1024 + kk];
          else if (kk < 2048) v = ahbp[bb*1024 + (kk-1024)];
          else if (kk < 2560) v = ctxS[bb*512 + (kk-2048)];
          else if (kk < 3072) v = ctxbS[bb*512 + (kk-2560)];
          else                v = dhS[bb*1024 + (kk-3072)];
          xs[bb][k] = v;
        }
      __syncthreads();
#pragma unroll
      for (int p = 0; p < 2; ++p) {
        int row = r0 + p*32 + w8*4 + q;
        if (row < r1) {
          int s1 = imin(k1, 3072);
          if (s1 > k0) acc[p] += dotseg(d_wih + (size_t)row*3072 + k0, &xs[b][0], s1 - k0);
          int h0 = imax(k0, 3072);
          if (k1 > h0) acc[p] += dotseg(d_whh + (size_t)row*1024 + (h0-3072), &xs[b][h0-k0], k1 - h0);
        }
      }
      __syncthreads();
    }
#pragma unroll
    for (int p = 0; p < 2; ++p) {
      int row = r0 + p*32 + w8*4 + q;
      if (row < r1) gout[(size_t)row*16 + b] = acc[p];
    }
  } else {
    if (t == 0) return;  // drnnb(t-1)
    int di = bid - 190;
    int r0 = di*4096/66, r1 = (di+1)*4096/66;  // <=63 rows
    const float* ahbp = ws + o_ahb + (size_t)((t-1)&1)*(B_*ARNN_);
    const float* ctxbS= ws + o_ctxb;
    const float* dhbS = ws + o_dhb;
    float* gout = ws + o_gdb;
    float acc[2] = {0.f, 0.f};
    for (int k0 = 0; k0 < 2560; k0 += 960) {
      int k1 = imin(2560, k0 + 960), n = k1 - k0;
      for (int bb = 0; bb < 16; ++bb)
        for (int k = tid; k < n; k += 512) {
          int kk = k0 + k; float v;
          if (kk < 1024)      v = ahbp[bb*1024 + kk];
          else if (kk < 1536) v = ctxbS[bb*512 + (kk-1024)];
          else                v = dhbS[bb*1024 + (kk-1536)];
          xs[bb][k] = v;
        }
      __syncthreads();
#pragma unroll
      for (int p = 0; p < 2; ++p) {
        int row = r0 + p*32 + w8*4 + q;
        if (row < r1) {
          int s1 = imin(k1, 1536);
          if (s1 > k0) acc[p] += dotseg(db_wih + (size_t)row*1536 + k0, &xs[b][0], s1 - k0);
          int h0 = imax(k0, 1536);
          if (k1 > h0) acc[p] += dotseg(db_whh + (size_t)row*1024 + (h0-1536), &xs[b][h0-k0], k1 - h0);
        }
      }
      __syncthreads();
    }
#pragma unroll
    for (int p = 0; p < 2; ++p) {
      int row = r0 + p*32 + w8*4 + q;
      if (row < r1) gout[(size_t)row*16 + b] = acc[p];
    }
  }
}

// ================= per-step kernel 2: attention(t) x2 + drnn(t-1) pointwise =================
__global__ __launch_bounds__(512) void k_step2(
    int t, const float* __restrict__ memory, const float* __restrict__ embeddings,
    const float* __restrict__ a_conv, const float* __restrict__ a_loc, const float* __restrict__ a_v,
    const float* __restrict__ ab_conv, const float* __restrict__ ab_loc, const float* __restrict__ ab_v,
    const float* __restrict__ d_b, const float* __restrict__ db_b,
    float* __restrict__ ws, float* __restrict__ out)
{
  __shared__ float ah_l[1024];
  __shared__ float pqp[4][128];
  __shared__ float pq_s[128];
  __shared__ float awp[2][TENC_+32];
  __shared__ float cw_s[NF_*2*KCV_];
  __shared__ float vv[128];
  __shared__ float fmT[TENC_][NF_];
  __shared__ float ep[TENC_][2];
  __shared__ float wl[TENC_];
  __shared__ float smx[2];
  int bid = blockIdx.x, tid = threadIdx.x;

  if (bid < 32) {
    if (t >= TOUT_) return;
    bool isB = bid >= 16; int b = bid & 15;
    int T = isB ? TBERT_ : TENC_;
    const float* mem   = isB ? embeddings : memory;
    const float* pmemB = ws + (isB ? o_pbert : o_pmem);
    const float* qWT   = ws + (isB ? o_qWTb : o_qWTa);
    const float* convW = isB ? ab_conv : a_conv;
    const float* locW  = isB ? ab_loc : a_loc;
    const float* vW    = isB ? ab_v : a_v;
    const float* hq = ws + (isB ? o_ahb : o_ah) + (size_t)(t&1)*(B_*ARNN_) + b*ARNN_;
    float* awS  = ws + (isB ? o_awb : o_aw) + b*T;
    float* awcS = ws + (isB ? o_awcb : o_awc) + b*T;
    float* ctxS = ws + (isB ? o_ctxb : o_ctx) + b*ENC_;
    float* ctxAll = ws + (isB ? o_ctxball : o_ctxall) + ((size_t)t*16 + b)*ENC_;
    float* alOut = out + (isB ? OO_ALB : OO_AL) + ((size_t)b*TOUT_ + t)*T;

    for (int i = tid; i < 1024; i += 512) ah_l[i] = hq[i];
    for (int i = tid; i < NF_*2*KCV_; i += 512) cw_s[i] = convW[i];
    for (int i = tid; i < 128; i += 512) vv[i] = vW[i];
    for (int i = tid; i < T + 30; i += 512) {
      bool in = (i >= 15) && (i < T + 15);
      awp[0][i] = in ? awS[i-15] : 0.f;
      awp[1][i] = in ? awcS[i-15] : 0.f;
    }
    __syncthreads();
    {  // pq = ah @ qW^T via pre-transposed qWT
      int a = tid & 127, hf = tid >> 7;
      float acc = 0;
      for (int k = hf*256; k < hf*256 + 256; ++k) acc = fmaf(qWT[(size_t)k*128 + a], ah_l[k], acc);
      pqp[hf][a] = acc;
    }
    __syncthreads();
    if (tid < 128) pq_s[tid] = pqp[0][tid] + pqp[1][tid] + pqp[2][tid] + pqp[3][tid];
    __syncthreads();
    // location conv -> fmT[t][f]
    for (int idx = tid; idx < T*NF_; idx += 512) {
      int tt = idx >> 5, f = idx & 31;
      const float* c0 = cw_s + f*62;
      float s = 0;
#pragma unroll
      for (int kk = 0; kk < 31; ++kk)
        s = fmaf(awp[0][tt+kk], c0[kk], fmaf(awp[1][tt+kk], c0[31+kk], s));
      fmT[tt][f] = s;
    }
    __syncthreads();
    // e[t] = sum_a v[a] * tanh(pq[a] + ploc[t,a] + pmem[b,t,a])
    {
      int a = tid & 127;
      float la[32];
#pragma unroll
      for (int f = 0; f < 32; ++f) la[f] = locW[a*32 + f];
      float pqr = pq_s[a], vr = vv[a];
      for (int idx = tid; idx < T*128; idx += 512) {
        int tt = idx >> 7;
        float pl = 0;
#pragma unroll
        for (int f = 0; f < 32; ++f) pl = fmaf(fmT[tt][f], la[f], pl);
        float s = vr * tanhf(pqr + pl + pmemB[((size_t)b*T + tt)*128 + a]);
#pragma unroll
        for (int off = 1; off < 64; off <<= 1) s += __shfl_xor(s, off);
        if ((tid & 63) == 0) ep[tt][(idx >> 6) & 1] = s;
      }
    }
    __syncthreads();
    if (tid < 64) {  // softmax stats
      float m = -1e30f;
      for (int i = tid; i < T; i += 64) m = fmaxf(m, ep[i][0] + ep[i][1]);
#pragma unroll
      for (int off = 1; off < 64; off <<= 1) m = fmaxf(m, __shfl_xor(m, off));
      float ssum = 0;
      for (int i = tid; i < T; i += 64) ssum += expf(ep[i][0] + ep[i][1] - m);
#pragma unroll
      for (int off = 1; off < 64; off <<= 1) ssum += __shfl_xor(ssum, off);
      if (tid == 0) { smx[0] = m; smx[1] = 1.f / ssum; }
    }
    __syncthreads();
    for (int i = tid; i < T; i += 512) {
      float wv = expf(ep[i][0] + ep[i][1] - smx[0]) * smx[1];
      wl[i] = wv;
      awS[i] = wv;
      awcS[i] += wv;
      alOut[i] = wv;
    }
    __syncthreads();
    {  // ctx = w @ mem   (tid == enc dim, exactly 512)
      float acc = 0;
      for (int tt = 0; tt < T; ++tt) acc = fmaf(wl[tt], mem[((size_t)b*T + tt)*512 + tid], acc);
      ctxS[tid] = acc;
      ctxAll[tid] = acc;
    }
  } else {
    if (t == 0) return;  // drnn/drnnb (t-1) pointwise
    int gid = (bid - 32)*512 + tid;
#pragma unroll
    for (int r = 0; r < 2; ++r) {
      int uf = gid + r*16384;
      int L = uf >> 14;
      int rem = uf & 16383;
      int u = rem >> 4, b = rem & 15;
      const float* g = ws + (L ? o_gdb : o_gd);
      const float* bias = L ? db_b : d_b;
      float* h  = ws + (L ? o_dhb : o_dh);
      float* cc = ws + (L ? o_dcb : o_dc);
      float gi = g[(size_t)u*16 + b]        + bias[u];
      float gf = g[(size_t)(1024+u)*16 + b] + bias[1024+u];
      float gg = g[(size_t)(2048+u)*16 + b] + bias[2048+u];
      float go = g[(size_t)(3072+u)*16 + b] + bias[3072+u];
      float co = cc[b*1024 + u];
      float cn = sigf(gf)*co + sigf(gi)*tanhf(gg);
      float hn = sigf(go)*tanhf(cn);
      cc[b*1024 + u] = cn;
      h[b*1024 + u] = hn;
      if (L == 0) ws[o_dhall + ((size_t)(t-1)*16 + b)*1024 + u] = hn;
    }
  }
}

// ================= epilog: batched projection + gate =================
__global__ __launch_bounds__(512) void k_proj(
    const float* __restrict__ pw, const float* __restrict__ pb,
    const float* __restrict__ gw, const float* __restrict__ gb,
    const float* __restrict__ ws, float* __restrict__ out)
{
  int t = blockIdx.x, tid = threadIdx.x;
  for (int o = tid; o < 16*81; o += 512) {
    int b = o / 81, j = o % 81;
    const float* wrow = (j < 80) ? (pw + (size_t)j*2048) : gw;
    const float* xd  = ws + o_dhall   + ((size_t)t*16 + b)*1024;
    const float* xc  = ws + o_ctxall  + ((size_t)t*16 + b)*512;
    const float* xcb = ws + o_ctxball + ((size_t)t*16 + b)*512;
    float acc = dotseg(wrow, xd, 1024) + dotseg(wrow + 1024, xc, 512)
              + dotseg(wrow + 1536, xcb, 512) + ((j < 80) ? pb[j] : gb[0]);
    if (j < 80) out[OO_MEL + ((size_t)b*80 + j)*200 + t] = acc;
    else        out[OO_GATE + (size_t)b*200 + t] = acc;
  }
}

extern "C" void kernel_launch(void* const* d_in, const int* in_sizes, int n_in,
                              void* d_out, int out_size, void* d_ws, size_t ws_size,
                              hipStream_t stream) {
  (void)in_sizes; (void)n_in; (void)out_size; (void)ws_size;
  const float* memory   = (const float*)d_in[0];
  const float* embeddings = (const float*)d_in[1];
  const float* dec      = (const float*)d_in[2];
  const float* pw1      = (const float*)d_in[3];
  const float* pw2      = (const float*)d_in[4];
  const float* pbw1     = (const float*)d_in[5];
  const float* pbw2     = (const float*)d_in[6];
  const float* a_wih    = (const float*)d_in[7];
  const float* a_whh    = (const float*)d_in[8];
  const float* a_b      = (const float*)d_in[9];
  const float* ab_wih   = (const float*)d_in[10];
  const float* ab_whh   = (const float*)d_in[11];
  const float* ab_b     = (const float*)d_in[12];
  const float* a_q      = (const float*)d_in[13];
  const float* a_m      = (const float*)d_in[14];
  const float* a_conv   = (const float*)d_in[15];
  const float* a_loc    = (const float*)d_in[16];
  const float* a_v      = (const float*)d_in[17];
  const float* ab_q     = (const float*)d_in[18];
  const float* ab_m     = (const float*)d_in[19];
  const float* ab_conv  = (const float*)d_in[20];
  const float* ab_loc   = (const float*)d_in[21];
  const float* ab_v     = (const float*)d_in[22];
  const float* d_wih    = (const float*)d_in[23];
  const float* d_whh    = (const float*)d_in[24];
  const float* d_b      = (const float*)d_in[25];
  const float* db_wih   = (const float*)d_in[26];
  const float* db_whh   = (const float*)d_in[27];
  const float* db_b     = (const float*)d_in[28];
  const float* proj_w   = (const float*)d_in[29];
  const float* proj_b   = (const float*)d_in[30];
  const float* gate_w   = (const float*)d_in[31];
  const float* gate_b   = (const float*)d_in[32];
  float* ws  = (float*)d_ws;
  float* out = (float*)d_out;

  k_prolog<<<dim3(474), dim3(256), 0, stream>>>(dec, pw1, pw2, pbw1, pbw2,
      memory, embeddings, a_m, ab_m, a_q, ab_q, ws);
  for (int t = 0; t <= TOUT_; ++t) {
    k_step1<<<dim3(256), dim3(512), 0, stream>>>(t,
        a_wih, a_whh, a_b, ab_wih, ab_whh, ab_b, d_wih, d_whh, db_wih, db_whh, ws);
    k_step2<<<dim3(64), dim3(512), 0, stream>>>(t, memory, embeddings,
        a_conv, a_loc, a_v, ab_conv, ab_loc, ab_v, d_b, db_b, ws, out);
  }
  k_proj<<<dim3(200), dim3(512), 0, stream>>>(proj_w, proj_b, gate_w, gate_b, ws, out);
}

// Round 2
// 34277.066 us; speedup vs baseline: 1.3708x; 1.3708x over previous
//
#include <hip/hip_runtime.h>
#include <cstdint>
#include <cmath>

#define DEVI __device__ __forceinline__

constexpr int B_ = 16, TENC_ = 168, TBERT_ = 96, TOUT_ = 200;
constexpr int NMEL_ = 80, ENC_ = 512, ARNN_ = 1024, PRE_ = 256, ATT_ = 128, NF_ = 32, KCV_ = 31;

// ---------------- workspace layout (float offsets) ----------------
constexpr size_t o_qWTa = 0;                               // [1024][128] transposed attn_q
constexpr size_t o_qWTb = o_qWTa + 1024*128;
constexpr size_t o_pall  = o_qWTb + 1024*128;              // [T][B][PRE]
constexpr size_t o_pball = o_pall + (size_t)TOUT_*B_*PRE_;
constexpr size_t o_pmem  = o_pball + (size_t)TOUT_*B_*PRE_; // [B][TENC][ATT]
constexpr size_t o_pbert = o_pmem + (size_t)B_*TENC_*ATT_;  // [B][TBERT][ATT]
constexpr size_t o_state = o_pbert + (size_t)B_*TBERT_*ATT_;
constexpr size_t o_ah   = o_state;                  // [2][B][ARNN] double-buffered (h: [b][u])
constexpr size_t o_ahb  = o_ah  + 2*B_*ARNN_;
constexpr size_t o_ac   = o_ahb + 2*B_*ARNN_;       // c: [u][b] layout
constexpr size_t o_acb  = o_ac  + B_*ARNN_;
constexpr size_t o_dh   = o_acb + B_*ARNN_;         // [b][u]
constexpr size_t o_dc   = o_dh  + B_*ARNN_;         // [u][b]
constexpr size_t o_dhb  = o_dc  + B_*ARNN_;         // [b][u]
constexpr size_t o_dcb  = o_dhb + B_*ARNN_;         // [u][b]
constexpr size_t o_ctx  = o_dcb + B_*ARNN_;         // [B][ENC]
constexpr size_t o_ctxb = o_ctx + B_*ENC_;
constexpr size_t o_aw   = o_ctxb+ B_*ENC_;          // [B][TENC]
constexpr size_t o_awc  = o_aw  + B_*TENC_;
constexpr size_t o_awb  = o_awc + B_*TENC_;         // [B][TBERT]
constexpr size_t o_awcb = o_awb + B_*TBERT_;
constexpr size_t o_zend = o_awcb+ B_*TBERT_;
constexpr size_t ZCOUNT = o_zend - o_state;
constexpr size_t o_gd   = o_zend;                   // drnn gates [4096][B]
constexpr size_t o_gdb  = o_gd + 4096*B_;
constexpr size_t o_dhall   = o_gdb + 4096*B_;       // [T][B][DRNN]
constexpr size_t o_ctxall  = o_dhall + (size_t)TOUT_*B_*ARNN_;
constexpr size_t o_ctxball = o_ctxall + (size_t)TOUT_*B_*ENC_;

// output offsets (floats)
constexpr size_t OO_MEL  = 0;
constexpr size_t OO_GATE = (size_t)B_*NMEL_*TOUT_;
constexpr size_t OO_AL   = OO_GATE + (size_t)B_*TOUT_;
constexpr size_t OO_ALB  = OO_AL + (size_t)B_*TOUT_*TENC_;

DEVI float sigf(float x) { return 1.f / (1.f + expf(-x)); }

DEVI float dotseg(const float* __restrict__ w, const float* __restrict__ x, int n) {
  const float4* wp = reinterpret_cast<const float4*>(w);
  const float4* xp = reinterpret_cast<const float4*>(x);
  float a0 = 0, a1 = 0, a2 = 0, a3 = 0;
  int n4 = n >> 2;
#pragma unroll 4
  for (int i = 0; i < n4; ++i) {
    float4 wv = wp[i], xv = xp[i];
    a0 = fmaf(wv.x, xv.x, a0); a1 = fmaf(wv.y, xv.y, a1);
    a2 = fmaf(wv.z, xv.z, a2); a3 = fmaf(wv.w, xv.w, a3);
  }
  return (a0 + a1) + (a2 + a3);
}

// ================= prolog: prenet(all t), pmem, pbert, q-transposes, zero states =================
__global__ __launch_bounds__(256) void k_prolog(
    const float* __restrict__ dec, const float* __restrict__ pw1, const float* __restrict__ pw2,
    const float* __restrict__ pbw1, const float* __restrict__ pbw2,
    const float* __restrict__ memory, const float* __restrict__ embeddings,
    const float* __restrict__ am, const float* __restrict__ abm,
    const float* __restrict__ aq, const float* __restrict__ abq,
    float* __restrict__ ws)
{
  __shared__ float smem[10240];
  int bid = blockIdx.x, tid = threadIdx.x;
  if (bid < 200) {
    int t = bid;
    float* xl  = smem;                // [16][80]
    float* h1  = smem + 1280;         // [16][256]
    float* h1b = smem + 1280 + 4096;  // [16][256]
    for (int i = tid; i < 16*80; i += 256) {
      int b = i / 80, m = i % 80;
      xl[i] = (t == 0) ? 0.f : dec[((size_t)b*80 + m)*200 + (t-1)];
    }
    __syncthreads();
    int j = tid;
    for (int b = 0; b < 16; ++b) {
      const float* x = xl + b*80;
      float a1 = 0, a2 = 0;
#pragma unroll 4
      for (int m = 0; m < 80; ++m) { a1 = fmaf(pw1[j*80+m], x[m], a1); a2 = fmaf(pbw1[j*80+m], x[m], a2); }
      h1[b*256+j]  = fmaxf(a1, 0.f);
      h1b[b*256+j] = fmaxf(a2, 0.f);
    }
    __syncthreads();
    for (int b = 0; b < 16; ++b) {
      float a1 = 0, a2 = 0;
#pragma unroll 4
      for (int k = 0; k < 256; ++k) { a1 = fmaf(pw2[j*256+k], h1[b*256+k], a1); a2 = fmaf(pbw2[j*256+k], h1b[b*256+k], a2); }
      ws[o_pall  + ((size_t)t*16+b)*256 + j] = fmaxf(a1, 0.f);
      ws[o_pball + ((size_t)t*16+b)*256 + j] = fmaxf(a2, 0.f);
    }
  } else if (bid < 368) {
    int r0 = (bid - 200) * 16;
    float* ml = smem;  // [16][512]
    for (int i = tid; i < 16*512; i += 256) ml[i] = memory[(size_t)r0*512 + i];
    __syncthreads();
    int a = tid & 127, ro = tid >> 7;
    for (int row = ro; row < 16; row += 2) {
      const float* x = ml + row*512; const float* w = am + (size_t)a*512;
      float acc = 0;
#pragma unroll 4
      for (int e = 0; e < 512; ++e) acc = fmaf(w[e], x[e], acc);
      ws[o_pmem + (size_t)(r0+row)*128 + a] = acc;
    }
  } else if (bid < 464) {
    int r0 = (bid - 368) * 16;
    float* ml = smem;
    for (int i = tid; i < 16*512; i += 256) ml[i] = embeddings[(size_t)r0*512 + i];
    __syncthreads();
    int a = tid & 127, ro = tid >> 7;
    for (int row = ro; row < 16; row += 2) {
      const float* x = ml + row*512; const float* w = abm + (size_t)a*512;
      float acc = 0;
#pragma unroll 4
      for (int e = 0; e < 512; ++e) acc = fmaf(w[e], x[e], acc);
      ws[o_pbert + (size_t)(r0+row)*128 + a] = acc;
    }
  } else if (bid < 466) {
    const float* src = (bid == 464) ? aq : abq;
    float* dst = ws + ((bid == 464) ? o_qWTa : o_qWTb);
    for (int i = tid; i < 1024*128; i += 256) {
      int k = i >> 7, a = i & 127;
      dst[i] = src[(size_t)a*1024 + k];
    }
  } else {
    int zi = bid - 466;  // 8 zero blocks
    for (size_t i = (size_t)zi*256 + tid; i < ZCOUNT; i += 8*256) ws[o_state + i] = 0.f;
  }
}

// ================= per-step kernel 1: all LSTM gate GEMMs (k-coalesced) =================
// 512 blocks x 256 thr. type = bid>>7: 0=arnn(t) 1=arnnb(t) 2=drnn(t-1) 3=drnnb(t-1)
// Block owns 8 units x 4 gates x 16 batch. Wave wv = gate, lane = k-slice.
// acc[8 rows][16 b] registers; x in LDS chunks of 512; w loads 1KiB coalesced/instr.

DEVI void compute_group(const float4* __restrict__ xsf, int g, int lane,
                        const float4 w[8], float acc[8][16]) {
#pragma unroll
  for (int b = 0; b < 16; ++b) {
    float4 xv = xsf[b*130 + g*64 + lane];
#pragma unroll
    for (int r = 0; r < 8; ++r) {
      acc[r][b] = fmaf(w[r].x, xv.x, acc[r][b]);
      acc[r][b] = fmaf(w[r].y, xv.y, acc[r][b]);
      acc[r][b] = fmaf(w[r].z, xv.z, acc[r][b]);
      acc[r][b] = fmaf(w[r].w, xv.w, acc[r][b]);
    }
  }
}

template<int IH>
DEVI void lstm_gates(const float* __restrict__ Wih, const float* __restrict__ Whh,
                     const float* const pieces[4], const int plens[4], int np,
                     const float* __restrict__ hp,
                     int u0, int wvi, int lane, int tid, float* __restrict__ smem,
                     float acc[8][16])
{
#pragma unroll 1
  for (int sub = 0; sub < 2; ++sub) {
    const float* W = sub ? Whh : Wih;
    const int len = sub ? 1024 : IH;
#pragma unroll 1
    for (int c0 = 0; c0 < len; c0 += 512) {
      const int n = (len - c0 < 512) ? (len - c0) : 512;   // 256 or 512, never straddles
      __syncthreads();
      if (sub == 0) {
#pragma unroll 1
        for (int b = 0; b < 16; ++b)
          for (int k = tid; k < n; k += 256) {
            int off = c0 + k;
            const float* src = pieces[0]; int L = plens[0];
            if (np > 1 && off >= L) {
              off -= L; src = pieces[1]; L = plens[1];
              if (np > 2 && off >= L) {
                off -= L; src = pieces[2]; L = plens[2];
                if (np > 3 && off >= L) { off -= L; src = pieces[3]; L = plens[3]; }
              }
            }
            smem[b*520 + k] = src[(size_t)b*L + off];
          }
      } else {
#pragma unroll 1
        for (int b = 0; b < 16; ++b)
          for (int k = tid; k < n; k += 256)
            smem[b*520 + k] = hp[b*1024 + c0 + k];
      }
      __syncthreads();
      const int ng = n >> 8;
      const float* wbase = W + (size_t)(wvi*1024 + u0)*len + c0 + 4*lane;
      const float4* xsf = (const float4*)smem;
      float4 w0[8], w1[8];
#pragma unroll
      for (int r = 0; r < 8; ++r) w0[r] = *(const float4*)(wbase + (size_t)r*len);
      if (ng == 2) {
#pragma unroll
        for (int r = 0; r < 8; ++r) w1[r] = *(const float4*)(wbase + (size_t)r*len + 256);
        compute_group(xsf, 0, lane, w0, acc);
        compute_group(xsf, 1, lane, w1, acc);
      } else {
        compute_group(xsf, 0, lane, w0, acc);
      }
    }
  }
}

// within-wave reduce: 64 k-partials -> outputs. res[ph] valid on lanes (holds full sum on all).
DEVI void wave_reduce(float acc[8][16], float* __restrict__ red, int lane, float res[4]) {
  int o = lane & 31, half = lane >> 5;
#pragma unroll
  for (int ph = 0; ph < 4; ++ph) {
#pragma unroll
    for (int j = 0; j < 32; ++j)
      red[j*68 + lane] = acc[2*ph + (j >> 4)][j & 15];
    float s = 0;
    const float* rrow = red + o*68 + half*32;
#pragma unroll
    for (int j = 0; j < 8; ++j) {
      float4 v = *(const float4*)(rrow + 4*j);
      s += (v.x + v.y) + (v.z + v.w);
    }
    res[ph] = s + __shfl_xor(s, 32);
  }
}

__global__ __launch_bounds__(256, 2) void k_step1(
    int t,
    const float* __restrict__ a_wih, const float* __restrict__ a_whh, const float* __restrict__ a_b,
    const float* __restrict__ ab_wih, const float* __restrict__ ab_whh, const float* __restrict__ ab_b,
    const float* __restrict__ d_wih, const float* __restrict__ d_whh,
    const float* __restrict__ db_wih, const float* __restrict__ db_whh,
    float* __restrict__ ws)
{
  __shared__ __align__(16) float smem[8704];   // xs[16][520] / red[4][32][68]
  __shared__ float gbuf[512];                   // [gate][unit j][b]
  int bid = blockIdx.x, tid = threadIdx.x;
  int wvi = tid >> 6, lane = tid & 63;
  int type = bid >> 7, idx = bid & 127, u0 = idx * 8;

  float acc[8][16];
#pragma unroll
  for (int r = 0; r < 8; ++r)
#pragma unroll
    for (int b = 0; b < 16; ++b) acc[r][b] = 0.f;

  float res[4];
  int o = lane & 31;

  if (type <= 1) {
    if (t >= TOUT_) return;
    bool isB = (type == 1);
    const float* pieces[4] = { ws + (isB ? o_pball : o_pall) + (size_t)t*B_*PRE_,
                               ws + (isB ? o_ctxb : o_ctx), nullptr, nullptr };
    const int plens[4] = { 256, 512, 0, 0 };
    const float* hp = ws + (isB ? o_ahb : o_ah) + (size_t)((t+1)&1)*(B_*ARNN_);
    lstm_gates<768>(isB ? ab_wih : a_wih, isB ? ab_whh : a_whh, pieces, plens, 2, hp,
                    u0, wvi, lane, tid, smem, acc);
    __syncthreads();
    wave_reduce(acc, smem + wvi*(32*68), lane, res);
    const float* bias = isB ? ab_b : a_b;
#pragma unroll
    for (int ph = 0; ph < 4; ++ph) {
      if (lane < 32) {
        int j = 2*ph + (o >> 4), b = o & 15;
        gbuf[wvi*128 + j*16 + b] = res[ph] + bias[wvi*1024 + u0 + j];
      }
    }
    __syncthreads();
    if (tid < 128) {
      int j = tid >> 4, b = tid & 15, u = u0 + j;
      float gi = gbuf[0*128 + j*16 + b], gf = gbuf[1*128 + j*16 + b];
      float gg = gbuf[2*128 + j*16 + b], go = gbuf[3*128 + j*16 + b];
      float* cst  = ws + (isB ? o_acb : o_ac);
      float* hcur = ws + (isB ? o_ahb : o_ah) + (size_t)(t&1)*(B_*ARNN_);
      float co = cst[u*16 + b];
      float cn = sigf(gf)*co + sigf(gi)*tanhf(gg);
      float hn = sigf(go)*tanhf(cn);
      cst[u*16 + b] = cn;
      hcur[b*1024 + u] = hn;
    }
  } else if (type == 2) {
    if (t == 0) return;  // drnn for step t-1
    const float* pieces[4] = { ws + o_ah  + (size_t)((t-1)&1)*(B_*ARNN_),
                               ws + o_ahb + (size_t)((t-1)&1)*(B_*ARNN_),
                               ws + o_ctx, ws + o_ctxb };
    const int plens[4] = { 1024, 1024, 512, 512 };
    lstm_gates<3072>(d_wih, d_whh, pieces, plens, 4, ws + o_dh,
                     u0, wvi, lane, tid, smem, acc);
    __syncthreads();
    wave_reduce(acc, smem + wvi*(32*68), lane, res);
    float* gout = ws + o_gd;
#pragma unroll
    for (int ph = 0; ph < 4; ++ph)
      if (lane < 32)
        gout[(size_t)(wvi*1024 + u0 + 2*ph + (o >> 4))*16 + (o & 15)] = res[ph];
  } else {
    if (t == 0) return;  // drnnb for step t-1
    const float* pieces[4] = { ws + o_ahb + (size_t)((t-1)&1)*(B_*ARNN_),
                               ws + o_ctxb, nullptr, nullptr };
    const int plens[4] = { 1024, 512, 0, 0 };
    lstm_gates<1536>(db_wih, db_whh, pieces, plens, 2, ws + o_dhb,
                     u0, wvi, lane, tid, smem, acc);
    __syncthreads();
    wave_reduce(acc, smem + wvi*(32*68), lane, res);
    float* gout = ws + o_gdb;
#pragma unroll
    for (int ph = 0; ph < 4; ++ph)
      if (lane < 32)
        gout[(size_t)(wvi*1024 + u0 + 2*ph + (o >> 4))*16 + (o & 15)] = res[ph];
  }
}

// ================= per-step kernel 2: attention(t) x2 + drnn(t-1) pointwise =================
__global__ __launch_bounds__(512) void k_step2(
    int t, const float* __restrict__ memory, const float* __restrict__ embeddings,
    const float* __restrict__ a_conv, const float* __restrict__ a_loc, const float* __restrict__ a_v,
    const float* __restrict__ ab_conv, const float* __restrict__ ab_loc, const float* __restrict__ ab_v,
    const float* __restrict__ d_b, const float* __restrict__ db_b,
    float* __restrict__ ws, float* __restrict__ out)
{
  __shared__ float ah_l[1024];
  __shared__ float pqp[4][128];
  __shared__ float pq_s[128];
  __shared__ float awp[2][TENC_+32];
  __shared__ float cw_s[NF_*2*KCV_];
  __shared__ float vv[128];
  __shared__ float fmT[TENC_][NF_];
  __shared__ float ep[TENC_][2];
  __shared__ float wl[TENC_];
  __shared__ float smx[2];
  int bid = blockIdx.x, tid = threadIdx.x;

  if (bid < 32) {
    if (t >= TOUT_) return;
    bool isB = bid >= 16; int b = bid & 15;
    int T = isB ? TBERT_ : TENC_;
    const float* mem   = isB ? embeddings : memory;
    const float* pmemB = ws + (isB ? o_pbert : o_pmem);
    const float* qWT   = ws + (isB ? o_qWTb : o_qWTa);
    const float* convW = isB ? ab_conv : a_conv;
    const float* locW  = isB ? ab_loc : a_loc;
    const float* vW    = isB ? ab_v : a_v;
    const float* hq = ws + (isB ? o_ahb : o_ah) + (size_t)(t&1)*(B_*ARNN_) + b*ARNN_;
    float* awS  = ws + (isB ? o_awb : o_aw) + b*T;
    float* awcS = ws + (isB ? o_awcb : o_awc) + b*T;
    float* ctxS = ws + (isB ? o_ctxb : o_ctx) + b*ENC_;
    float* ctxAll = ws + (isB ? o_ctxball : o_ctxall) + ((size_t)t*16 + b)*ENC_;
    float* alOut = out + (isB ? OO_ALB : OO_AL) + ((size_t)b*TOUT_ + t)*T;

    for (int i = tid; i < 1024; i += 512) ah_l[i] = hq[i];
    for (int i = tid; i < NF_*2*KCV_; i += 512) cw_s[i] = convW[i];
    for (int i = tid; i < 128; i += 512) vv[i] = vW[i];
    for (int i = tid; i < T + 30; i += 512) {
      bool in = (i >= 15) && (i < T + 15);
      awp[0][i] = in ? awS[i-15] : 0.f;
      awp[1][i] = in ? awcS[i-15] : 0.f;
    }
    __syncthreads();
    {
      int a = tid & 127, hf = tid >> 7;
      float acc = 0;
      for (int k = hf*256; k < hf*256 + 256; ++k) acc = fmaf(qWT[(size_t)k*128 + a], ah_l[k], acc);
      pqp[hf][a] = acc;
    }
    __syncthreads();
    if (tid < 128) pq_s[tid] = pqp[0][tid] + pqp[1][tid] + pqp[2][tid] + pqp[3][tid];
    __syncthreads();
    for (int idx = tid; idx < T*NF_; idx += 512) {
      int tt = idx >> 5, f = idx & 31;
      const float* c0 = cw_s + f*62;
      float s = 0;
#pragma unroll
      for (int kk = 0; kk < 31; ++kk)
        s = fmaf(awp[0][tt+kk], c0[kk], fmaf(awp[1][tt+kk], c0[31+kk], s));
      fmT[tt][f] = s;
    }
    __syncthreads();
    {
      int a = tid & 127;
      float la[32];
#pragma unroll
      for (int f = 0; f < 32; ++f) la[f] = locW[a*32 + f];
      float pqr = pq_s[a], vr = vv[a];
      for (int idx = tid; idx < T*128; idx += 512) {
        int tt = idx >> 7;
        float pl = 0;
#pragma unroll
        for (int f = 0; f < 32; ++f) pl = fmaf(fmT[tt][f], la[f], pl);
        float s = vr * tanhf(pqr + pl + pmemB[((size_t)b*T + tt)*128 + a]);
#pragma unroll
        for (int off = 1; off < 64; off <<= 1) s += __shfl_xor(s, off);
        if ((tid & 63) == 0) ep[tt][(idx >> 6) & 1] = s;
      }
    }
    __syncthreads();
    if (tid < 64) {
      float m = -1e30f;
      for (int i = tid; i < T; i += 64) m = fmaxf(m, ep[i][0] + ep[i][1]);
#pragma unroll
      for (int off = 1; off < 64; off <<= 1) m = fmaxf(m, __shfl_xor(m, off));
      float ssum = 0;
      for (int i = tid; i < T; i += 64) ssum += expf(ep[i][0] + ep[i][1] - m);
#pragma unroll
      for (int off = 1; off < 64; off <<= 1) ssum += __shfl_xor(ssum, off);
      if (tid == 0) { smx[0] = m; smx[1] = 1.f / ssum; }
    }
    __syncthreads();
    for (int i = tid; i < T; i += 512) {
      float wv = expf(ep[i][0] + ep[i][1] - smx[0]) * smx[1];
      wl[i] = wv;
      awS[i] = wv;
      awcS[i] += wv;
      alOut[i] = wv;
    }
    __syncthreads();
    {  // ctx = w @ mem, 4-way ILP
      float a0 = 0, a1 = 0, a2 = 0, a3 = 0;
      const float* mb = mem + (size_t)b*T*512 + tid;
      int tt = 0;
      for (; tt + 4 <= T; tt += 4) {
        a0 = fmaf(wl[tt],   mb[(size_t)tt*512],     a0);
        a1 = fmaf(wl[tt+1], mb[(size_t)(tt+1)*512], a1);
        a2 = fmaf(wl[tt+2], mb[(size_t)(tt+2)*512], a2);
        a3 = fmaf(wl[tt+3], mb[(size_t)(tt+3)*512], a3);
      }
      for (; tt < T; ++tt) a0 = fmaf(wl[tt], mb[(size_t)tt*512], a0);
      float acc = (a0 + a1) + (a2 + a3);
      ctxS[tid] = acc;
      ctxAll[tid] = acc;
    }
  } else {
    if (t == 0) return;  // drnn/drnnb (t-1) pointwise
    int gid = (bid - 32)*512 + tid;
#pragma unroll
    for (int r = 0; r < 2; ++r) {
      int uf = gid + r*16384;
      int L = uf >> 14;
      int rem = uf & 16383;
      int u = rem >> 4, b = rem & 15;
      const float* g = ws + (L ? o_gdb : o_gd);
      const float* bias = L ? db_b : d_b;
      float* h  = ws + (L ? o_dhb : o_dh);
      float* cc = ws + (L ? o_dcb : o_dc);
      float gi = g[(size_t)u*16 + b]        + bias[u];
      float gf = g[(size_t)(1024+u)*16 + b] + bias[1024+u];
      float gg = g[(size_t)(2048+u)*16 + b] + bias[2048+u];
      float go = g[(size_t)(3072+u)*16 + b] + bias[3072+u];
      float co = cc[u*16 + b];
      float cn = sigf(gf)*co + sigf(gi)*tanhf(gg);
      float hn = sigf(go)*tanhf(cn);
      cc[u*16 + b] = cn;
      h[b*1024 + u] = hn;
      if (L == 0) ws[o_dhall + ((size_t)(t-1)*16 + b)*1024 + u] = hn;
    }
  }
}

// ================= epilog: batched projection + gate =================
__global__ __launch_bounds__(512) void k_proj(
    const float* __restrict__ pw, const float* __restrict__ pb,
    const float* __restrict__ gw, const float* __restrict__ gb,
    const float* __restrict__ ws, float* __restrict__ out)
{
  int t = blockIdx.x, tid = threadIdx.x;
  for (int o = tid; o < 16*81; o += 512) {
    int b = o / 81, j = o % 81;
    const float* wrow = (j < 80) ? (pw + (size_t)j*2048) : gw;
    const float* xd  = ws + o_dhall   + ((size_t)t*16 + b)*1024;
    const float* xc  = ws + o_ctxall  + ((size_t)t*16 + b)*512;
    const float* xcb = ws + o_ctxball + ((size_t)t*16 + b)*512;
    float acc = dotseg(wrow, xd, 1024) + dotseg(wrow + 1024, xc, 512)
              + dotseg(wrow + 1536, xcb, 512) + ((j < 80) ? pb[j] : gb[0]);
    if (j < 80) out[OO_MEL + ((size_t)b*80 + j)*200 + t] = acc;
    else        out[OO_GATE + (size_t)b*200 + t] = acc;
  }
}

extern "C" void kernel_launch(void* const* d_in, const int* in_sizes, int n_in,
                              void* d_out, int out_size, void* d_ws, size_t ws_size,
                              hipStream_t stream) {
  (void)in_sizes; (void)n_in; (void)out_size; (void)ws_size;
  const float* memory   = (const float*)d_in[0];
  const float* embeddings = (const float*)d_in[1];
  const float* dec      = (const float*)d_in[2];
  const float* pw1      = (const float*)d_in[3];
  const float* pw2      = (const float*)d_in[4];
  const float* pbw1     = (const float*)d_in[5];
  const float* pbw2     = (const float*)d_in[6];
  const float* a_wih    = (const float*)d_in[7];
  const float* a_whh    = (const float*)d_in[8];
  const float* a_b      = (const float*)d_in[9];
  const float* ab_wih   = (const float*)d_in[10];
  const float* ab_whh   = (const float*)d_in[11];
  const float* ab_b     = (const float*)d_in[12];
  const float* a_q      = (const float*)d_in[13];
  const float* a_m      = (const float*)d_in[14];
  const float* a_conv   = (const float*)d_in[15];
  const float* a_loc    = (const float*)d_in[16];
  const float* a_v      = (const float*)d_in[17];
  const float* ab_q     = (const float*)d_in[18];
  const float* ab_m     = (const float*)d_in[19];
  const float* ab_conv  = (const float*)d_in[20];
  const float* ab_loc   = (const float*)d_in[21];
  const float* ab_v     = (const float*)d_in[22];
  const float* d_wih    = (const float*)d_in[23];
  const float* d_whh    = (const float*)d_in[24];
  const float* d_b      = (const float*)d_in[25];
  const float* db_wih   = (const float*)d_in[26];
  const float* db_whh   = (const float*)d_in[27];
  const float* db_b     = (const float*)d_in[28];
  const float* proj_w   = (const float*)d_in[29];
  const float* proj_b   = (const float*)d_in[30];
  const float* gate_w   = (const float*)d_in[31];
  const float* gate_b   = (const float*)d_in[32];
  float* ws  = (float*)d_ws;
  float* out = (float*)d_out;

  k_prolog<<<dim3(474), dim3(256), 0, stream>>>(dec, pw1, pw2, pbw1, pbw2,
      memory, embeddings, a_m, ab_m, a_q, ab_q, ws);
  for (int t = 0; t <= TOUT_; ++t) {
    k_step1<<<dim3(512), dim3(256), 0, stream>>>(t,
        a_wih, a_whh, a_b, ab_wih, ab_whh, ab_b, d_wih, d_whh, db_wih, db_whh, ws);
    k_step2<<<dim3(64), dim3(512), 0, stream>>>(t, memory, embeddings,
        a_conv, a_loc, a_v, ab_conv, ab_loc, ab_v, d_b, db_b, ws, out);
  }
  k_proj<<<dim3(200), dim3(512), 0, stream>>>(proj_w, proj_b, gate_w, gate_b, ws, out);
}